// Round 1
// baseline (1696.886 us; speedup 1.0000x reference)
//
#include <hip/hip_runtime.h>
#include <hip/hip_bf16.h>

// Attention: B=4,H=16,S=2048,D=64. Inputs fp32 Q,K,V [B,H,S,D], mask int32 [B,1,S,S].
// Outputs: out [B,H,S,D] then p_attn [B,H,S,S], fp32, concatenated in d_out.
// Strategy: bf16 MFMA for both GEMMs. Pre-pass: Q,K -> bf16 (same layout),
// V -> bf16 transposed per head (Vt[d][k]) so PV B-fragments are contiguous.
// Main kernel: one block per (bh, 16 q-rows); scores live in 32 C-fragments
// per wave (wave owns 512 keys); softmax in registers + shfl + small LDS;
// P round-trips through LDS (bf16) for the C-layout -> A-layout transform.

#define SDIM 2048
#define DDIM 64
#define NB 4
#define NH 16
#define BHN 64
#define TQ 16
#define OUT_ELEMS (BHN * SDIM * DDIM)   // 8388608

typedef float f32x4 __attribute__((ext_vector_type(4)));
typedef __bf16 bf16x8 __attribute__((ext_vector_type(8)));
typedef __bf16 bf16;

__global__ void cvt_bf16_kernel(const float* __restrict__ src, bf16* __restrict__ dst, int n8) {
    int i = blockIdx.x * blockDim.x + threadIdx.x;
    if (i >= n8) return;
    const float4* s4 = (const float4*)src;
    float4 a = s4[2 * i];
    float4 c = s4[2 * i + 1];
    bf16x8 o;
    o[0] = (bf16)a.x; o[1] = (bf16)a.y; o[2] = (bf16)a.z; o[3] = (bf16)a.w;
    o[4] = (bf16)c.x; o[5] = (bf16)c.y; o[6] = (bf16)c.z; o[7] = (bf16)c.w;
    *(bf16x8*)(dst + 8 * (size_t)i) = o;
}

// V [bh][k][d] fp32 -> Vt [bh][d][k] bf16. Grid: BHN * (SDIM/64), block 256.
__global__ void transpose_v_kernel(const float* __restrict__ v, bf16* __restrict__ vt) {
    int bh = blockIdx.x >> 5;          // SDIM/64 = 32 tiles
    int k0 = (blockIdx.x & 31) * 64;
    __shared__ bf16 tile[64][72];      // [d][k_local], padded
    int t = threadIdx.x;
    int r = t >> 4;                    // 0..15
    int c4 = (t & 15) * 4;             // 0..60
    const float* vb = v + (size_t)bh * SDIM * DDIM;
#pragma unroll
    for (int i = 0; i < 4; i++) {
        int row = r + 16 * i;
        float4 x = *(const float4*)(vb + (size_t)(k0 + row) * DDIM + c4);
        tile[c4 + 0][row] = (bf16)x.x;
        tile[c4 + 1][row] = (bf16)x.y;
        tile[c4 + 2][row] = (bf16)x.z;
        tile[c4 + 3][row] = (bf16)x.w;
    }
    __syncthreads();
    bf16* vtb = vt + (size_t)bh * DDIM * SDIM;
    int drow = t >> 2;                 // 0..63
    int seg = (t & 3) * 16;            // 16 bf16 = 32B per thread
    uint4 u0 = *(const uint4*)&tile[drow][seg];
    uint4 u1 = *(const uint4*)&tile[drow][seg + 8];
    *(uint4*)(vtb + (size_t)drow * SDIM + k0 + seg) = u0;
    *(uint4*)(vtb + (size_t)drow * SDIM + k0 + seg + 8) = u1;
}

__launch_bounds__(256, 2)
__global__ void attn_kernel(const bf16* __restrict__ Qb, const bf16* __restrict__ Kb,
                            const bf16* __restrict__ Vtb, const int* __restrict__ mask,
                            float* __restrict__ out, float* __restrict__ p_out) {
    const int bid = blockIdx.x;
    const int qt = bid & 127;          // q-tile within head
    const int bh = bid >> 7;           // 0..63
    const int b  = bh >> 4;            // batch (H=16)
    const int t = threadIdx.x;
    const int w = t >> 6;              // wave 0..3
    const int lane = t & 63;
    const int quad = lane >> 4;
    const int l15 = lane & 15;

    __shared__ bf16 pb[TQ * 2056];     // P tile bf16, padded stride (+16B/row)
    __shared__ float redmax[4][16];
    __shared__ float redsum[4][16];

    // ---- Q A-fragments (shared across the wave's key tiles) ----
    const int qrow = qt * TQ + l15;
    const bf16* qbase = Qb + ((size_t)bh * SDIM + qrow) * DDIM + 8 * quad;
    bf16x8 aq0 = *(const bf16x8*)(qbase);        // d = 0..31 slice
    bf16x8 aq1 = *(const bf16x8*)(qbase + 32);   // d = 32..63 slice

    // ---- QK^T: wave w owns keys [512w, 512w+512) as 32 16-key tiles ----
    f32x4 acc[32];
    const bf16* kbase = Kb + ((size_t)bh * SDIM + w * 512 + l15) * DDIM + 8 * quad;
#pragma unroll
    for (int kt = 0; kt < 32; kt++) {
        const bf16* kp = kbase + (size_t)kt * 16 * DDIM;
        bf16x8 b0 = *(const bf16x8*)(kp);
        bf16x8 b1 = *(const bf16x8*)(kp + 32);
        f32x4 c = {0.f, 0.f, 0.f, 0.f};
        c = __builtin_amdgcn_mfma_f32_16x16x32_bf16(aq0, b0, c, 0, 0, 0);
        c = __builtin_amdgcn_mfma_f32_16x16x32_bf16(aq1, b1, c, 0, 0, 0);
        acc[kt] = c;
    }

    // ---- scale + mask + row max (C layout: row = 4*quad+r, col = l15) ----
    const int* mrow = mask + (size_t)b * SDIM * SDIM
                      + (size_t)(qt * TQ + quad * 4) * SDIM + w * 512 + l15;
    float mx[4] = {-3e38f, -3e38f, -3e38f, -3e38f};
#pragma unroll
    for (int kt = 0; kt < 32; kt++) {
#pragma unroll
        for (int r = 0; r < 4; r++) {
            int m = mrow[(size_t)r * SDIM + kt * 16];
            float s = (m == 1) ? -100000000.0f : acc[kt][r] * 0.125f;
            acc[kt][r] = s;
            mx[r] = fmaxf(mx[r], s);
        }
    }
#pragma unroll
    for (int off = 1; off < 16; off <<= 1) {
#pragma unroll
        for (int r = 0; r < 4; r++)
            mx[r] = fmaxf(mx[r], __shfl_xor(mx[r], off, 64));
    }
    if (l15 == 0) {
#pragma unroll
        for (int r = 0; r < 4; r++) redmax[w][quad * 4 + r] = mx[r];
    }
    __syncthreads();
#pragma unroll
    for (int r = 0; r < 4; r++) {
        mx[r] = fmaxf(fmaxf(redmax[0][quad * 4 + r], redmax[1][quad * 4 + r]),
                      fmaxf(redmax[2][quad * 4 + r], redmax[3][quad * 4 + r]));
    }

    // ---- exp + row sum ----
    float sm[4] = {0.f, 0.f, 0.f, 0.f};
#pragma unroll
    for (int kt = 0; kt < 32; kt++) {
#pragma unroll
        for (int r = 0; r < 4; r++) {
            float e = __expf(acc[kt][r] - mx[r]);
            acc[kt][r] = e;
            sm[r] += e;
        }
    }
#pragma unroll
    for (int off = 1; off < 16; off <<= 1) {
#pragma unroll
        for (int r = 0; r < 4; r++)
            sm[r] += __shfl_xor(sm[r], off, 64);
    }
    if (l15 == 0) {
#pragma unroll
        for (int r = 0; r < 4; r++) redsum[w][quad * 4 + r] = sm[r];
    }
    __syncthreads();
#pragma unroll
    for (int r = 0; r < 4; r++) {
        sm[r] = 1.0f / (redsum[0][quad * 4 + r] + redsum[1][quad * 4 + r]
                        + redsum[2][quad * 4 + r] + redsum[3][quad * 4 + r]);
    }

    // ---- normalize: write p_attn (fp32, global) + P (bf16, LDS) ----
    float* prow = p_out + (size_t)bh * SDIM * SDIM
                  + (size_t)(qt * TQ + quad * 4) * SDIM + w * 512 + l15;
#pragma unroll
    for (int kt = 0; kt < 32; kt++) {
#pragma unroll
        for (int r = 0; r < 4; r++) {
            float p = acc[kt][r] * sm[r];
            prow[(size_t)r * SDIM + kt * 16] = p;
            pb[(quad * 4 + r) * 2056 + w * 512 + kt * 16 + l15] = (bf16)p;
        }
    }
    __syncthreads();

    // ---- PV: wave w computes out cols [16w, 16w+16) over all 2048 keys ----
    f32x4 o = {0.f, 0.f, 0.f, 0.f};
    const bf16* vbase = Vtb + ((size_t)bh * DDIM + w * 16 + l15) * SDIM + 8 * quad;
    const bf16* pbase = pb + l15 * 2056 + 8 * quad;
#pragma unroll 8
    for (int ks = 0; ks < 64; ks++) {
        bf16x8 a  = *(const bf16x8*)(pbase + 32 * ks);
        bf16x8 bv = *(const bf16x8*)(vbase + 32 * ks);
        o = __builtin_amdgcn_mfma_f32_16x16x32_bf16(a, bv, o, 0, 0, 0);
    }
    float* orow = out + ((size_t)bh * SDIM + qt * TQ + quad * 4) * DDIM + w * 16 + l15;
#pragma unroll
    for (int r = 0; r < 4; r++) orow[(size_t)r * DDIM] = o[r];
}

extern "C" void kernel_launch(void* const* d_in, const int* in_sizes, int n_in,
                              void* d_out, int out_size, void* d_ws, size_t ws_size,
                              hipStream_t stream) {
    const float* q = (const float*)d_in[0];
    const float* k = (const float*)d_in[1];
    const float* v = (const float*)d_in[2];
    const int* mask = (const int*)d_in[3];
    float* out = (float*)d_out;
    float* p = out + (size_t)OUT_ELEMS;

    bf16* Qb  = (bf16*)d_ws;                          // 16 MB
    bf16* Kb  = Qb + (size_t)BHN * SDIM * DDIM;       // 16 MB
    bf16* Vtb = Kb + (size_t)BHN * SDIM * DDIM;       // 16 MB  (total 48 MB of d_ws)

    cvt_bf16_kernel<<<4096, 256, 0, stream>>>(q, Qb, OUT_ELEMS / 8);
    cvt_bf16_kernel<<<4096, 256, 0, stream>>>(k, Kb, OUT_ELEMS / 8);
    transpose_v_kernel<<<BHN * (SDIM / 64), 256, 0, stream>>>(v, Vtb);
    attn_kernel<<<BHN * (SDIM / TQ), 256, 0, stream>>>(Qb, Kb, Vtb, mask, out, p);
}